// Round 1
// baseline (144.650 us; speedup 1.0000x reference)
//
#include <hip/hip_runtime.h>
#include <cstdint>

#define CCLS 10
#define DDIM 256

// Pack y[N,10] (values {0,1}) into a 10-bit keep mask per node: bit c set iff y[n,c]==0.
__global__ void pack_mask_kernel(const int* __restrict__ y, uint32_t* __restrict__ km, int N) {
    __shared__ int sy[256 * CCLS];
    const int base = blockIdx.x * 256;
    const int total = N * CCLS;
    // coalesced staging of 2560 contiguous ints
    for (int i = threadIdx.x; i < 256 * CCLS; i += 256) {
        int idx = base * CCLS + i;
        sy[i] = (idx < total) ? y[idx] : 1;
    }
    __syncthreads();
    const int n = base + threadIdx.x;
    if (n < N) {
        uint32_t m = 0;
        #pragma unroll
        for (int c = 0; c < CCLS; ++c)
            m |= (sy[threadIdx.x * CCLS + c] == 0 ? 1u : 0u) << c;
        km[n] = m;
    }
}

// Each block: one v, one contiguous chunk of rows. 256 threads = 4 waves.
// Wave w handles rows n0+w, n0+w+4, ... (whole wave shares one row -> mask is
// wave-uniform, readfirstlane to SGPR). Lane d4 loads float4 at d=[4*d4,4*d4+4).
template <bool USE_KM>
__global__ __launch_bounds__(256, 4) void masked_sum_kernel(
    const float* __restrict__ x,      // [V, N, D]
    const uint32_t* __restrict__ km,  // [N] packed keep mask (if USE_KM)
    const int* __restrict__ y,        // [N, C] fallback
    float* __restrict__ out,          // [V, C*D], pre-zeroed
    int N, int rows_per_chunk)
{
    const int v = blockIdx.y;
    const int chunk = blockIdx.x;
    const int n0 = chunk * rows_per_chunk;
    const int n1 = min(n0 + rows_per_chunk, N);
    const int row = threadIdx.x >> 6;   // wave id 0..3
    const int d4  = threadIdx.x & 63;   // float4 index within row

    float acc[CCLS][4];
    #pragma unroll
    for (int c = 0; c < CCLS; ++c)
        #pragma unroll
        for (int j = 0; j < 4; ++j) acc[c][j] = 0.0f;

    const float4* __restrict__ xbase =
        reinterpret_cast<const float4*>(x + (size_t)v * N * DDIM);

    for (int n = n0 + row; n < n1; n += 4) {
        float4 xv = xbase[(size_t)n * (DDIM / 4) + d4];
        uint32_t m;
        if (USE_KM) {
            m = km[n];
        } else {
            m = 0;
            #pragma unroll
            for (int c = 0; c < CCLS; ++c)
                m |= (y[n * CCLS + c] == 0 ? 1u : 0u) << c;
        }
        m = __builtin_amdgcn_readfirstlane(m);  // wave-uniform
        #pragma unroll
        for (int c = 0; c < CCLS; ++c) {
            float kf = (float)((m >> c) & 1u);
            acc[c][0] = fmaf(kf, xv.x, acc[c][0]);
            acc[c][1] = fmaf(kf, xv.y, acc[c][1]);
            acc[c][2] = fmaf(kf, xv.z, acc[c][2]);
            acc[c][3] = fmaf(kf, xv.w, acc[c][3]);
        }
    }

    // Block-level reduction in LDS (collapses the 4 waves), then one global
    // atomicAdd per output element per block.
    __shared__ float lred[CCLS * DDIM];  // 10 KB
    for (int i = threadIdx.x; i < CCLS * DDIM; i += 256) lred[i] = 0.0f;
    __syncthreads();
    #pragma unroll
    for (int c = 0; c < CCLS; ++c)
        #pragma unroll
        for (int j = 0; j < 4; ++j)
            atomicAdd(&lred[c * DDIM + d4 * 4 + j], acc[c][j]);
    __syncthreads();
    float* __restrict__ outv = out + (size_t)v * CCLS * DDIM;
    for (int i = threadIdx.x; i < CCLS * DDIM; i += 256)
        atomicAdd(&outv[i], lred[i]);
}

extern "C" void kernel_launch(void* const* d_in, const int* in_sizes, int n_in,
                              void* d_out, int out_size, void* d_ws, size_t ws_size,
                              hipStream_t stream) {
    const int*   y = (const int*)d_in[0];         // [N, 10]
    const float* x = (const float*)d_in[1];       // [V, N, 256]
    float* out = (float*)d_out;                   // [V, 2560]

    const int N = in_sizes[0] / CCLS;             // 200000
    const int V = in_sizes[1] / (N * DDIM);       // 2

    hipMemsetAsync(d_out, 0, (size_t)out_size * sizeof(float), stream);

    const bool use_km = ws_size >= (size_t)N * sizeof(uint32_t);
    uint32_t* km = (uint32_t*)d_ws;

    if (use_km) {
        pack_mask_kernel<<<(N + 255) / 256, 256, 0, stream>>>(y, km, N);
    }

    const int P = 512;                            // chunks per view
    const int rpc = (N + P - 1) / P;              // rows per chunk
    dim3 grid(P, V);
    if (use_km)
        masked_sum_kernel<true><<<grid, 256, 0, stream>>>(x, km, y, out, N, rpc);
    else
        masked_sum_kernel<false><<<grid, 256, 0, stream>>>(x, nullptr, y, out, N, rpc);
}

// Round 2
// 129.607 us; speedup vs baseline: 1.1161x; 1.1161x over previous
//
#include <hip/hip_runtime.h>
#include <cstdint>

#define CCLS 10
#define DDIM 256
#define NCHUNK 512

// ---------------------------------------------------------------------------
// Pack y[N,10] (values {0,1}) into a 10-bit keep mask per node: bit c iff y==0.
__global__ void pack_mask_kernel(const int* __restrict__ y, uint32_t* __restrict__ km, int N) {
    __shared__ int sy[256 * CCLS];
    const int base = blockIdx.x * 256;
    const int total = N * CCLS;
    for (int i = threadIdx.x; i < 256 * CCLS; i += 256) {
        int idx = base * CCLS + i;
        sy[i] = (idx < total) ? y[idx] : 1;
    }
    __syncthreads();
    const int n = base + threadIdx.x;
    if (n < N) {
        uint32_t m = 0;
        #pragma unroll
        for (int c = 0; c < CCLS; ++c)
            m |= (sy[threadIdx.x * CCLS + c] == 0 ? 1u : 0u) << c;
        km[n] = m;
    }
}

// ---------------------------------------------------------------------------
// Main kernel. Block = (chunk, v). 256 threads = 4 waves; wave w owns rows
// n0+w, n0+w+4, ...  Whole wave shares a row -> mask is wave-uniform (SGPR).
// Lane d4 holds float4 at d=[4*d4, 4*d4+4).
// EPI==0: plain-store per-block partials to ws (preferred, no atomics)
// EPI==1: atomicAdd into out (fallback, needs pre-zeroed out), mask from km
// EPI==2: like 1 but mask computed inline from y (no ws at all)
template <int EPI>
__global__ __launch_bounds__(256, 4) void masked_sum_kernel(
    const float* __restrict__ x,      // [V, N, D]
    const uint32_t* __restrict__ km,  // [N]
    const int* __restrict__ y,        // [N, C]
    float* __restrict__ dst,          // EPI==0: partials [V, NCHUNK, C*D]; else out [V, C*D]
    int N, int rows_per_chunk, int nchunk)
{
    const int v = blockIdx.y;
    const int chunk = blockIdx.x;
    const int n0 = chunk * rows_per_chunk;
    const int n1 = min(n0 + rows_per_chunk, N);
    const int row = threadIdx.x >> 6;   // wave id 0..3
    const int d4  = threadIdx.x & 63;   // float4 index within row

    float acc[CCLS][4];
    #pragma unroll
    for (int c = 0; c < CCLS; ++c)
        #pragma unroll
        for (int j = 0; j < 4; ++j) acc[c][j] = 0.0f;

    const float4* __restrict__ xbase =
        reinterpret_cast<const float4*>(x + (size_t)v * N * DDIM);

    auto inline_mask = [&](int n) -> uint32_t {
        uint32_t m = 0;
        #pragma unroll
        for (int c = 0; c < CCLS; ++c)
            m |= (y[n * CCLS + c] == 0 ? 1u : 0u) << c;
        return m;
    };

    int n = n0 + row;
    // 2 rows per iteration: both loads in flight before either mask is used.
    for (; n + 4 < n1; n += 8) {
        float4 x0 = xbase[(size_t)n * (DDIM / 4) + d4];
        float4 x1 = xbase[(size_t)(n + 4) * (DDIM / 4) + d4];
        uint32_t m0, m1;
        if (EPI < 2) { m0 = km[n]; m1 = km[n + 4]; }
        else         { m0 = inline_mask(n); m1 = inline_mask(n + 4); }
        m0 = __builtin_amdgcn_readfirstlane(m0);
        m1 = __builtin_amdgcn_readfirstlane(m1);
        #pragma unroll
        for (int c = 0; c < CCLS; ++c) {
            const float k0 = ((m0 >> c) & 1u) ? 1.0f : 0.0f;  // SALU cselect
            acc[c][0] = fmaf(k0, x0.x, acc[c][0]);
            acc[c][1] = fmaf(k0, x0.y, acc[c][1]);
            acc[c][2] = fmaf(k0, x0.z, acc[c][2]);
            acc[c][3] = fmaf(k0, x0.w, acc[c][3]);
        }
        #pragma unroll
        for (int c = 0; c < CCLS; ++c) {
            const float k1 = ((m1 >> c) & 1u) ? 1.0f : 0.0f;
            acc[c][0] = fmaf(k1, x1.x, acc[c][0]);
            acc[c][1] = fmaf(k1, x1.y, acc[c][1]);
            acc[c][2] = fmaf(k1, x1.z, acc[c][2]);
            acc[c][3] = fmaf(k1, x1.w, acc[c][3]);
        }
    }
    if (n < n1) {
        float4 x0 = xbase[(size_t)n * (DDIM / 4) + d4];
        uint32_t m0 = (EPI < 2) ? km[n] : inline_mask(n);
        m0 = __builtin_amdgcn_readfirstlane(m0);
        #pragma unroll
        for (int c = 0; c < CCLS; ++c) {
            const float k0 = ((m0 >> c) & 1u) ? 1.0f : 0.0f;
            acc[c][0] = fmaf(k0, x0.x, acc[c][0]);
            acc[c][1] = fmaf(k0, x0.y, acc[c][1]);
            acc[c][2] = fmaf(k0, x0.z, acc[c][2]);
            acc[c][3] = fmaf(k0, x0.w, acc[c][3]);
        }
    }

    // Cross-wave reduction: plain writes, one sync, plain reads. 40 KB LDS
    // => exactly 4 blocks/CU at 160 KB.
    __shared__ float lred[4 * CCLS * DDIM];
    float4* l4 = reinterpret_cast<float4*>(lred);
    #pragma unroll
    for (int c = 0; c < CCLS; ++c)
        l4[row * (CCLS * 64) + c * 64 + d4] =
            make_float4(acc[c][0], acc[c][1], acc[c][2], acc[c][3]);
    __syncthreads();

    #pragma unroll
    for (int k = 0; k < CCLS; ++k) {
        const int i = k * 256 + threadIdx.x;
        const float s = (lred[i] + lred[2560 + i]) + (lred[5120 + i] + lred[7680 + i]);
        if (EPI == 0)
            dst[((size_t)v * nchunk + chunk) * (CCLS * DDIM) + i] = s;
        else
            atomicAdd(&dst[(size_t)v * (CCLS * DDIM) + i], s);
    }
}

// ---------------------------------------------------------------------------
// out[v, i] = sum over chunks of part[v, chunk, i]
__global__ void reduce_parts_kernel(const float* __restrict__ part,
                                    float* __restrict__ out, int nchunk) {
    const int v = blockIdx.y;
    const int i = blockIdx.x * 256 + threadIdx.x;
    const float* __restrict__ b = part + (size_t)v * nchunk * (CCLS * DDIM) + i;
    float s0 = 0.f, s1 = 0.f, s2 = 0.f, s3 = 0.f;
    int p = 0;
    for (; p + 4 <= nchunk; p += 4) {
        s0 += b[(size_t)(p + 0) * (CCLS * DDIM)];
        s1 += b[(size_t)(p + 1) * (CCLS * DDIM)];
        s2 += b[(size_t)(p + 2) * (CCLS * DDIM)];
        s3 += b[(size_t)(p + 3) * (CCLS * DDIM)];
    }
    for (; p < nchunk; ++p) s0 += b[(size_t)p * (CCLS * DDIM)];
    out[(size_t)v * (CCLS * DDIM) + i] = (s0 + s1) + (s2 + s3);
}

// ---------------------------------------------------------------------------
extern "C" void kernel_launch(void* const* d_in, const int* in_sizes, int n_in,
                              void* d_out, int out_size, void* d_ws, size_t ws_size,
                              hipStream_t stream) {
    const int*   y = (const int*)d_in[0];         // [N, 10]
    const float* x = (const float*)d_in[1];       // [V, N, 256]
    float* out = (float*)d_out;                   // [V, 2560]

    const int N = in_sizes[0] / CCLS;             // 200000
    const int V = in_sizes[1] / (N * DDIM);       // 2

    const size_t km_bytes   = ((size_t)N * sizeof(uint32_t) + 255) & ~(size_t)255;
    const size_t part_bytes = (size_t)V * NCHUNK * CCLS * DDIM * sizeof(float);

    const int rpc = (N + NCHUNK - 1) / NCHUNK;
    dim3 grid(NCHUNK, V);

    if (ws_size >= km_bytes + part_bytes) {
        uint32_t* km = (uint32_t*)d_ws;
        float* part = (float*)((char*)d_ws + km_bytes);
        pack_mask_kernel<<<(N + 255) / 256, 256, 0, stream>>>(y, km, N);
        masked_sum_kernel<0><<<grid, 256, 0, stream>>>(x, km, y, part, N, rpc, NCHUNK);
        reduce_parts_kernel<<<dim3(CCLS * DDIM / 256, V), 256, 0, stream>>>(part, out, NCHUNK);
    } else if (ws_size >= km_bytes) {
        uint32_t* km = (uint32_t*)d_ws;
        hipMemsetAsync(d_out, 0, (size_t)out_size * sizeof(float), stream);
        pack_mask_kernel<<<(N + 255) / 256, 256, 0, stream>>>(y, km, N);
        masked_sum_kernel<1><<<grid, 256, 0, stream>>>(x, km, y, out, N, rpc, NCHUNK);
    } else {
        hipMemsetAsync(d_out, 0, (size_t)out_size * sizeof(float), stream);
        masked_sum_kernel<2><<<grid, 256, 0, stream>>>(x, nullptr, y, out, N, rpc, NCHUNK);
    }
}

// Round 3
// 83.570 us; speedup vs baseline: 1.7309x; 1.5509x over previous
//
#include <hip/hip_runtime.h>
#include <cstdint>

#define CCLS 10
#define DDIM 256
#define NCHUNK 512

typedef float f32x4 __attribute__((ext_vector_type(4)));

__device__ inline f32x4 ntload4(const f32x4* p) {
    return __builtin_nontemporal_load(p);
}
__device__ inline uint32_t rfl(uint32_t x) {
    return (uint32_t)__builtin_amdgcn_readfirstlane((int)x);
}

// ---------------------------------------------------------------------------
// Pack y[N,10] (values {0,1}) into a 10-bit keep mask per node: bit c iff y==0.
__global__ void pack_mask_kernel(const int* __restrict__ y, uint32_t* __restrict__ km, int N) {
    __shared__ int sy[256 * CCLS];
    const int base = blockIdx.x * 256;
    const int total = N * CCLS;
    for (int i = threadIdx.x; i < 256 * CCLS; i += 256) {
        int idx = base * CCLS + i;
        sy[i] = (idx < total) ? y[idx] : 1;
    }
    __syncthreads();
    const int n = base + threadIdx.x;
    if (n < N) {
        uint32_t m = 0;
        #pragma unroll
        for (int c = 0; c < CCLS; ++c)
            m |= (sy[threadIdx.x * CCLS + c] == 0 ? 1u : 0u) << c;
        km[n] = m;
    }
}

// ---------------------------------------------------------------------------
// Main kernel. Block = (chunk, v). 256 threads = 4 waves; wave w owns rows
// n0+w, n0+w+4, ...  Whole wave shares a row -> mask is wave-uniform (SGPR).
// Lane d4 holds the float4 at d=[4*d4, 4*d4+4).  4-row unroll: 4 KB of x in
// flight per wave before any consume.  x loaded nontemporal (streamed once).
// EPI==0: plain-store per-block partials to ws. EPI==2: inline mask + atomics.
template <int EPI>
__global__ __launch_bounds__(256, 4) void masked_sum_kernel(
    const float* __restrict__ x,      // [V, N, D]
    const uint32_t* __restrict__ km,  // [N]
    const int* __restrict__ y,        // [N, C] (EPI==2)
    float* __restrict__ dst,          // EPI==0: partials [V, NCHUNK, C*D]; else out
    int N, int rows_per_chunk, int nchunk)
{
    const int v = blockIdx.y;
    const int chunk = blockIdx.x;
    const int n0 = chunk * rows_per_chunk;
    const int n1 = min(n0 + rows_per_chunk, N);
    const int row = threadIdx.x >> 6;   // wave id 0..3
    const int d4  = threadIdx.x & 63;   // float4 index within row

    f32x4 acc[CCLS];
    #pragma unroll
    for (int c = 0; c < CCLS; ++c) acc[c] = (f32x4){0.f, 0.f, 0.f, 0.f};

    const f32x4* __restrict__ xb =
        reinterpret_cast<const f32x4*>(x + (size_t)v * N * DDIM);

    auto inline_mask = [&](int n) -> uint32_t {
        uint32_t m = 0;
        #pragma unroll
        for (int c = 0; c < CCLS; ++c)
            m |= (y[n * CCLS + c] == 0 ? 1u : 0u) << c;
        return m;
    };

    int n = n0 + row;
    for (; n + 12 < n1; n += 16) {
        f32x4 x0 = ntload4(xb + (size_t)(n)      * (DDIM / 4) + d4);
        f32x4 x1 = ntload4(xb + (size_t)(n + 4)  * (DDIM / 4) + d4);
        f32x4 x2 = ntload4(xb + (size_t)(n + 8)  * (DDIM / 4) + d4);
        f32x4 x3 = ntload4(xb + (size_t)(n + 12) * (DDIM / 4) + d4);
        uint32_t m0, m1, m2, m3;
        if (EPI == 0) { m0 = km[n]; m1 = km[n + 4]; m2 = km[n + 8]; m3 = km[n + 12]; }
        else { m0 = inline_mask(n); m1 = inline_mask(n + 4); m2 = inline_mask(n + 8); m3 = inline_mask(n + 12); }
        m0 = rfl(m0); m1 = rfl(m1); m2 = rfl(m2); m3 = rfl(m3);
        #pragma unroll
        for (int c = 0; c < CCLS; ++c)
            acc[c] += (((m0 >> c) & 1u) ? 1.0f : 0.0f) * x0;
        #pragma unroll
        for (int c = 0; c < CCLS; ++c)
            acc[c] += (((m1 >> c) & 1u) ? 1.0f : 0.0f) * x1;
        #pragma unroll
        for (int c = 0; c < CCLS; ++c)
            acc[c] += (((m2 >> c) & 1u) ? 1.0f : 0.0f) * x2;
        #pragma unroll
        for (int c = 0; c < CCLS; ++c)
            acc[c] += (((m3 >> c) & 1u) ? 1.0f : 0.0f) * x3;
    }
    for (; n < n1; n += 4) {
        f32x4 x0 = ntload4(xb + (size_t)n * (DDIM / 4) + d4);
        uint32_t m0 = (EPI == 0) ? km[n] : inline_mask(n);
        m0 = rfl(m0);
        #pragma unroll
        for (int c = 0; c < CCLS; ++c)
            acc[c] += (((m0 >> c) & 1u) ? 1.0f : 0.0f) * x0;
    }

    // Cross-wave reduction: plain writes, one sync, plain reads. 40 KB LDS.
    __shared__ f32x4 lred[4][CCLS][DDIM / 4];
    #pragma unroll
    for (int c = 0; c < CCLS; ++c)
        lred[row][c][d4] = acc[c];
    __syncthreads();

    const f32x4* __restrict__ lf = &lred[0][0][0];        // [4][640]
    if (EPI == 0) {
        f32x4* __restrict__ dstv = reinterpret_cast<f32x4*>(
            dst + ((size_t)v * nchunk + chunk) * (CCLS * DDIM));
        for (int j = threadIdx.x; j < CCLS * DDIM / 4; j += 256) {
            f32x4 s = (lf[j] + lf[640 + j]) + (lf[1280 + j] + lf[1920 + j]);
            dstv[j] = s;
        }
    } else {
        float* __restrict__ outv = dst + (size_t)v * (CCLS * DDIM);
        for (int j = threadIdx.x; j < CCLS * DDIM / 4; j += 256) {
            f32x4 s = (lf[j] + lf[640 + j]) + (lf[1280 + j] + lf[1920 + j]);
            atomicAdd(&outv[4 * j + 0], s.x);
            atomicAdd(&outv[4 * j + 1], s.y);
            atomicAdd(&outv[4 * j + 2], s.z);
            atomicAdd(&outv[4 * j + 3], s.w);
        }
    }
}

// ---------------------------------------------------------------------------
// Parallel partial reduction: grid (CD/256, V, 8). Block sums 64 chunks of its
// 256-float slice (wave w takes chunks p0+w*16 .. +16), LDS-reduces the 4
// waves, then 8-way atomicAdd into pre-zeroed out.
__global__ __launch_bounds__(256) void reduce_parts_kernel(
    const float* __restrict__ part, float* __restrict__ out, int nchunk)
{
    const int v = blockIdx.y, g = blockIdx.z;
    const int w = threadIdx.x >> 6, l = threadIdx.x & 63;
    const int i4 = blockIdx.x * 64 + l;  // f32x4 index in [0, 640)
    const f32x4* __restrict__ b =
        reinterpret_cast<const f32x4*>(part + (size_t)v * nchunk * (CCLS * DDIM));
    const int cpg = nchunk / 8;          // chunks per group (64)
    const int p0 = g * cpg + w * (cpg / 4);
    f32x4 s0 = {0.f,0.f,0.f,0.f}, s1 = s0, s2 = s0, s3 = s0;
    #pragma unroll
    for (int k = 0; k < cpg / 4; k += 4) {
        s0 += b[(size_t)(p0 + k + 0) * (CCLS * DDIM / 4) + i4];
        s1 += b[(size_t)(p0 + k + 1) * (CCLS * DDIM / 4) + i4];
        s2 += b[(size_t)(p0 + k + 2) * (CCLS * DDIM / 4) + i4];
        s3 += b[(size_t)(p0 + k + 3) * (CCLS * DDIM / 4) + i4];
    }
    f32x4 s = (s0 + s1) + (s2 + s3);
    __shared__ f32x4 lred[4][64];
    lred[w][l] = s;
    __syncthreads();
    if (w == 0) {
        f32x4 t = (lred[0][l] + lred[1][l]) + (lred[2][l] + lred[3][l]);
        float* o = out + (size_t)v * (CCLS * DDIM) + (size_t)i4 * 4;
        atomicAdd(o + 0, t.x);
        atomicAdd(o + 1, t.y);
        atomicAdd(o + 2, t.z);
        atomicAdd(o + 3, t.w);
    }
}

// ---------------------------------------------------------------------------
extern "C" void kernel_launch(void* const* d_in, const int* in_sizes, int n_in,
                              void* d_out, int out_size, void* d_ws, size_t ws_size,
                              hipStream_t stream) {
    const int*   y = (const int*)d_in[0];         // [N, 10]
    const float* x = (const float*)d_in[1];       // [V, N, 256]
    float* out = (float*)d_out;                   // [V, 2560]

    const int N = in_sizes[0] / CCLS;             // 200000
    const int V = in_sizes[1] / (N * DDIM);       // 2

    const size_t km_bytes   = ((size_t)N * sizeof(uint32_t) + 255) & ~(size_t)255;
    const size_t part_bytes = (size_t)V * NCHUNK * CCLS * DDIM * sizeof(float);

    const int rpc = (N + NCHUNK - 1) / NCHUNK;
    dim3 grid(NCHUNK, V);

    hipMemsetAsync(d_out, 0, (size_t)out_size * sizeof(float), stream);

    if (ws_size >= km_bytes + part_bytes) {
        uint32_t* km = (uint32_t*)d_ws;
        float* part = (float*)((char*)d_ws + km_bytes);
        pack_mask_kernel<<<(N + 255) / 256, 256, 0, stream>>>(y, km, N);
        masked_sum_kernel<0><<<grid, 256, 0, stream>>>(x, km, y, part, N, rpc, NCHUNK);
        reduce_parts_kernel<<<dim3(CCLS * DDIM / 256, V, 8), 256, 0, stream>>>(part, out, NCHUNK);
    } else {
        masked_sum_kernel<2><<<grid, 256, 0, stream>>>(x, nullptr, y, out, N, rpc, NCHUNK);
    }
}

// Round 4
// 78.052 us; speedup vs baseline: 1.8533x; 1.0707x over previous
//
#include <hip/hip_runtime.h>
#include <cstdint>

#define CCLS 10
#define DDIM 256
#define NCHUNK 256          // chunks per view -> 512 blocks total (2/CU)
#define UNR 8               // rows unrolled per wave in main loop

typedef float f32x4 __attribute__((ext_vector_type(4)));

__device__ inline f32x4 ntload4(const f32x4* p) {
    return __builtin_nontemporal_load(p);
}
__device__ inline uint32_t rfl(uint32_t x) {
    return (uint32_t)__builtin_amdgcn_readfirstlane((int)x);
}

// ---------------------------------------------------------------------------
// Pack y[N,10] (values {0,1}) into a 10-bit keep mask per node: bit c iff y==0.
__global__ void pack_mask_kernel(const int* __restrict__ y, uint32_t* __restrict__ km, int N) {
    __shared__ int sy[256 * CCLS];
    const int base = blockIdx.x * 256;
    const int total = N * CCLS;
    for (int i = threadIdx.x; i < 256 * CCLS; i += 256) {
        int idx = base * CCLS + i;
        sy[i] = (idx < total) ? y[idx] : 1;
    }
    __syncthreads();
    const int n = base + threadIdx.x;
    if (n < N) {
        uint32_t m = 0;
        #pragma unroll
        for (int c = 0; c < CCLS; ++c)
            m |= (sy[threadIdx.x * CCLS + c] == 0 ? 1u : 0u) << c;
        km[n] = m;
    }
}

// ---------------------------------------------------------------------------
// Main kernel. Block = (chunk, v). 256 threads = 4 waves; wave w owns rows
// n0+w, n0+w+4, ...  Whole wave shares a row -> mask is wave-uniform (SGPR).
// Lane d4 holds the float4 at d=[4*d4, 4*d4+4).  UNR-row unroll: 8 KB of x in
// flight per wave before any consume.  x loaded nontemporal (streamed once).
// EPI==0: plain-store per-block partials to ws. EPI==2: inline mask + atomics.
template <int EPI>
__global__ __launch_bounds__(256, 4) void masked_sum_kernel(
    const float* __restrict__ x,      // [V, N, D]
    const uint32_t* __restrict__ km,  // [N]
    const int* __restrict__ y,        // [N, C] (EPI==2)
    float* __restrict__ dst,          // EPI==0: partials [V, NCHUNK, C*D]; else out
    int N, int rows_per_chunk, int nchunk)
{
    const int v = blockIdx.y;
    const int chunk = blockIdx.x;
    const int n0 = chunk * rows_per_chunk;
    const int n1 = min(n0 + rows_per_chunk, N);
    const int row = threadIdx.x >> 6;   // wave id 0..3
    const int d4  = threadIdx.x & 63;   // float4 index within row

    f32x4 acc[CCLS];
    #pragma unroll
    for (int c = 0; c < CCLS; ++c) acc[c] = (f32x4){0.f, 0.f, 0.f, 0.f};

    const f32x4* __restrict__ xb =
        reinterpret_cast<const f32x4*>(x + (size_t)v * N * DDIM);

    auto inline_mask = [&](int n) -> uint32_t {
        uint32_t m = 0;
        #pragma unroll
        for (int c = 0; c < CCLS; ++c)
            m |= (y[n * CCLS + c] == 0 ? 1u : 0u) << c;
        return m;
    };

    int n = n0 + row;
    // UNR rows per iteration per wave (block covers 4*UNR consecutive rows).
    for (; n + 4 * (UNR - 1) < n1; n += 4 * UNR) {
        f32x4 xv[UNR];
        uint32_t mm[UNR];
        #pragma unroll
        for (int u = 0; u < UNR; ++u)
            xv[u] = ntload4(xb + (size_t)(n + 4 * u) * (DDIM / 4) + d4);
        #pragma unroll
        for (int u = 0; u < UNR; ++u)
            mm[u] = (EPI == 0) ? km[n + 4 * u] : inline_mask(n + 4 * u);
        #pragma unroll
        for (int u = 0; u < UNR; ++u) {
            const uint32_t m = rfl(mm[u]);
            #pragma unroll
            for (int c = 0; c < CCLS; ++c)
                acc[c] += (((m >> c) & 1u) ? 1.0f : 0.0f) * xv[u];
        }
    }
    for (; n < n1; n += 4) {
        f32x4 x0 = ntload4(xb + (size_t)n * (DDIM / 4) + d4);
        const uint32_t m = rfl((EPI == 0) ? km[n] : inline_mask(n));
        #pragma unroll
        for (int c = 0; c < CCLS; ++c)
            acc[c] += (((m >> c) & 1u) ? 1.0f : 0.0f) * x0;
    }

    // Cross-wave reduction: plain writes, one sync, plain reads. 40 KB LDS.
    __shared__ f32x4 lred[4][CCLS][DDIM / 4];
    #pragma unroll
    for (int c = 0; c < CCLS; ++c)
        lred[row][c][d4] = acc[c];
    __syncthreads();

    const f32x4* __restrict__ lf = &lred[0][0][0];        // [4][640]
    if (EPI == 0) {
        f32x4* __restrict__ dstv = reinterpret_cast<f32x4*>(
            dst + ((size_t)v * nchunk + chunk) * (CCLS * DDIM));
        for (int j = threadIdx.x; j < CCLS * DDIM / 4; j += 256) {
            f32x4 s = (lf[j] + lf[640 + j]) + (lf[1280 + j] + lf[1920 + j]);
            dstv[j] = s;
        }
    } else {
        float* __restrict__ outv = dst + (size_t)v * (CCLS * DDIM);
        for (int j = threadIdx.x; j < CCLS * DDIM / 4; j += 256) {
            f32x4 s = (lf[j] + lf[640 + j]) + (lf[1280 + j] + lf[1920 + j]);
            atomicAdd(&outv[4 * j + 0], s.x);
            atomicAdd(&outv[4 * j + 1], s.y);
            atomicAdd(&outv[4 * j + 2], s.z);
            atomicAdd(&outv[4 * j + 3], s.w);
        }
    }
}

// ---------------------------------------------------------------------------
// Deterministic final reduction, no atomics, no pre-zero needed.
// Grid (160, V), 256 threads = 4 waves.  Block owns 4 f32x4 output columns
// (160*4 = 640 = C*D/4).  Wave w covers chunks [w*64, (w+1)*64); lane l:
// col = bx*4 + (l&3), slot = l>>2 (16 slots); lane sums chunks w*64+slot+16j.
// shfl_xor over slot bits collapses 16 slots; LDS collapses 4 waves; the
// first 4 threads write the final f32x4 -> each out element written once.
__global__ __launch_bounds__(256) void reduce_parts_kernel(
    const float* __restrict__ part, float* __restrict__ out, int nchunk)
{
    const int v = blockIdx.y;
    const int w = threadIdx.x >> 6, l = threadIdx.x & 63;
    const int colbase = blockIdx.x * 4;
    const int col = colbase + (l & 3);            // f32x4 index in [0, 640)
    const int slot = l >> 2;                      // 0..15
    const int cpw = nchunk / 4;                   // chunks per wave (64)
    const f32x4* __restrict__ b =
        reinterpret_cast<const f32x4*>(part) + (size_t)v * nchunk * (CCLS * DDIM / 4);

    f32x4 s = (f32x4){0.f, 0.f, 0.f, 0.f};
    #pragma unroll 4
    for (int ch = w * cpw + slot; ch < (w + 1) * cpw; ch += 16)
        s += b[(size_t)ch * (CCLS * DDIM / 4) + col];

    // collapse the 16 slots (lane bits 2..5)
    #pragma unroll
    for (int off = 4; off < 64; off <<= 1) {
        s.x += __shfl_xor(s.x, off);
        s.y += __shfl_xor(s.y, off);
        s.z += __shfl_xor(s.z, off);
        s.w += __shfl_xor(s.w, off);
    }

    __shared__ f32x4 lred[4][4];
    if (l < 4) lred[w][l] = s;
    __syncthreads();
    if (threadIdx.x < 4) {
        f32x4 t = (lred[0][threadIdx.x] + lred[1][threadIdx.x]) +
                  (lred[2][threadIdx.x] + lred[3][threadIdx.x]);
        reinterpret_cast<f32x4*>(out)[(size_t)v * (CCLS * DDIM / 4) + colbase + threadIdx.x] = t;
    }
}

// ---------------------------------------------------------------------------
extern "C" void kernel_launch(void* const* d_in, const int* in_sizes, int n_in,
                              void* d_out, int out_size, void* d_ws, size_t ws_size,
                              hipStream_t stream) {
    const int*   y = (const int*)d_in[0];         // [N, 10]
    const float* x = (const float*)d_in[1];       // [V, N, 256]
    float* out = (float*)d_out;                   // [V, 2560]

    const int N = in_sizes[0] / CCLS;             // 200000
    const int V = in_sizes[1] / (N * DDIM);       // 2

    const size_t km_bytes   = ((size_t)N * sizeof(uint32_t) + 255) & ~(size_t)255;
    const size_t part_bytes = (size_t)V * NCHUNK * CCLS * DDIM * sizeof(float);

    const int rpc = (N + NCHUNK - 1) / NCHUNK;
    dim3 grid(NCHUNK, V);

    if (ws_size >= km_bytes + part_bytes) {
        uint32_t* km = (uint32_t*)d_ws;
        float* part = (float*)((char*)d_ws + km_bytes);
        pack_mask_kernel<<<(N + 255) / 256, 256, 0, stream>>>(y, km, N);
        masked_sum_kernel<0><<<grid, 256, 0, stream>>>(x, km, y, part, N, rpc, NCHUNK);
        reduce_parts_kernel<<<dim3(CCLS * DDIM / 4 / 4, V), 256, 0, stream>>>(part, out, NCHUNK);
    } else {
        hipMemsetAsync(d_out, 0, (size_t)out_size * sizeof(float), stream);
        masked_sum_kernel<2><<<grid, 256, 0, stream>>>(x, nullptr, y, out, N, rpc, NCHUNK);
    }
}

// Round 5
// 74.934 us; speedup vs baseline: 1.9304x; 1.0416x over previous
//
#include <hip/hip_runtime.h>
#include <cstdint>

#define CCLS 10
#define DDIM 256
#define NCHUNK 256          // chunks per view -> 512 blocks total (2/CU)
#define UNR 8               // rows unrolled per wave in main loop
#define RPC_MAX 800         // max rows per chunk the LDS mask table holds

typedef float f32x4 __attribute__((ext_vector_type(4)));

__device__ inline f32x4 ntload4(const f32x4* p) {
    return __builtin_nontemporal_load(p);
}
__device__ inline uint32_t rfl(uint32_t x) {
    return (uint32_t)__builtin_amdgcn_readfirstlane((int)x);
}

// ---------------------------------------------------------------------------
// Fused main kernel. Block = (chunk, v). 256 threads = 4 waves; wave w owns
// rows n0+w, n0+w+4, ...  Whole wave shares a row -> mask is wave-uniform.
// Block start: stage this chunk's y-slice -> 10-bit keep masks in LDS (once),
// with the first UNR x-loads already in flight to hide the staging latency.
// Hot loop: 1-deep software pipeline, UNR rows (8 KB/wave) in flight.
// EPI==0: plain-store per-block partials to ws. EPI==1: atomicAdd into
// pre-zeroed out (fallback when ws is too small).
template <int EPI>
__global__ __launch_bounds__(256, 2) void masked_sum_kernel(
    const float* __restrict__ x,      // [V, N, D]
    const int* __restrict__ y,        // [N, C]
    float* __restrict__ dst,          // EPI==0: partials [V, nchunk, C*D]; else out
    int N, int rows_per_chunk, int nchunk)
{
    const int v = blockIdx.y;
    const int chunk = blockIdx.x;
    const int n0 = chunk * rows_per_chunk;
    const int n1 = min(n0 + rows_per_chunk, N);
    const int nr = n1 - n0;
    const int row = threadIdx.x >> 6;   // wave id 0..3
    const int d4  = threadIdx.x & 63;   // float4 index within row

    __shared__ uint32_t smask[RPC_MAX];           // 3.2 KB
    __shared__ f32x4 lred[4][CCLS][DDIM / 4];     // 40 KB

    const f32x4* __restrict__ xb =
        reinterpret_cast<const f32x4*>(x + (size_t)v * N * DDIM);

    f32x4 acc[CCLS];
    #pragma unroll
    for (int c = 0; c < CCLS; ++c) acc[c] = (f32x4){0.f, 0.f, 0.f, 0.f};

    // --- issue iteration-0 x loads (latency overlaps the mask staging) ---
    int n = n0 + row;
    bool have = (n + 4 * (UNR - 1) < n1);
    f32x4 xv[UNR];
    if (have) {
        #pragma unroll
        for (int u = 0; u < UNR; ++u)
            xv[u] = ntload4(xb + (size_t)(n + 4 * u) * (DDIM / 4) + d4);
    }

    // --- stage masks: thread t handles rows t, t+256, ... (40 B/lane dense) ---
    for (int r = threadIdx.x; r < nr; r += 256) {
        const int* __restrict__ yr = y + (size_t)(n0 + r) * CCLS;
        uint32_t m = 0;
        #pragma unroll
        for (int c = 0; c < CCLS; ++c)
            m |= (yr[c] == 0 ? 1u : 0u) << c;
        smask[r] = m;
    }
    __syncthreads();

    // --- hot loop: 1-deep pipeline, UNR rows per wave per iteration ---
    while (have) {
        const int nn = n + 4 * UNR;
        const bool hnext = (nn + 4 * (UNR - 1) < n1);
        f32x4 xn[UNR];
        if (hnext) {
            #pragma unroll
            for (int u = 0; u < UNR; ++u)
                xn[u] = ntload4(xb + (size_t)(nn + 4 * u) * (DDIM / 4) + d4);
        }
        #pragma unroll
        for (int u = 0; u < UNR; ++u) {
            const uint32_t m = rfl(smask[n - n0 + 4 * u]);
            #pragma unroll
            for (int c = 0; c < CCLS; ++c)
                acc[c] += (((m >> c) & 1u) ? 1.0f : 0.0f) * xv[u];
        }
        #pragma unroll
        for (int u = 0; u < UNR; ++u) xv[u] = xn[u];
        n = nn; have = hnext;
    }
    // remainder rows
    for (; n < n1; n += 4) {
        f32x4 x0 = ntload4(xb + (size_t)n * (DDIM / 4) + d4);
        const uint32_t m = rfl(smask[n - n0]);
        #pragma unroll
        for (int c = 0; c < CCLS; ++c)
            acc[c] += (((m >> c) & 1u) ? 1.0f : 0.0f) * x0;
    }

    // --- cross-wave reduction: plain writes, one sync, plain reads ---
    #pragma unroll
    for (int c = 0; c < CCLS; ++c)
        lred[row][c][d4] = acc[c];
    __syncthreads();

    const f32x4* __restrict__ lf = &lred[0][0][0];        // [4][640]
    if (EPI == 0) {
        f32x4* __restrict__ dstv = reinterpret_cast<f32x4*>(
            dst + ((size_t)v * nchunk + chunk) * (CCLS * DDIM));
        for (int j = threadIdx.x; j < CCLS * DDIM / 4; j += 256) {
            f32x4 s = (lf[j] + lf[640 + j]) + (lf[1280 + j] + lf[1920 + j]);
            dstv[j] = s;
        }
    } else {
        float* __restrict__ outv = dst + (size_t)v * (CCLS * DDIM);
        for (int j = threadIdx.x; j < CCLS * DDIM / 4; j += 256) {
            f32x4 s = (lf[j] + lf[640 + j]) + (lf[1280 + j] + lf[1920 + j]);
            atomicAdd(&outv[4 * j + 0], s.x);
            atomicAdd(&outv[4 * j + 1], s.y);
            atomicAdd(&outv[4 * j + 2], s.z);
            atomicAdd(&outv[4 * j + 3], s.w);
        }
    }
}

// ---------------------------------------------------------------------------
// Deterministic final reduction, no atomics, no pre-zero needed.
// Grid (160, V), 256 threads = 4 waves.  Block owns 4 f32x4 output columns.
// Wave w covers chunks [w*cpw, (w+1)*cpw); lane l: col = bx*4 + (l&3),
// slot = l>>2; shfl_xor collapses the 16 slots; LDS collapses 4 waves.
__global__ __launch_bounds__(256) void reduce_parts_kernel(
    const float* __restrict__ part, float* __restrict__ out, int nchunk)
{
    const int v = blockIdx.y;
    const int w = threadIdx.x >> 6, l = threadIdx.x & 63;
    const int colbase = blockIdx.x * 4;
    const int col = colbase + (l & 3);            // f32x4 index in [0, 640)
    const int slot = l >> 2;                      // 0..15
    const int cpw = nchunk / 4;                   // chunks per wave
    const f32x4* __restrict__ b =
        reinterpret_cast<const f32x4*>(part) + (size_t)v * nchunk * (CCLS * DDIM / 4);

    f32x4 s = (f32x4){0.f, 0.f, 0.f, 0.f};
    #pragma unroll 4
    for (int ch = w * cpw + slot; ch < (w + 1) * cpw; ch += 16)
        s += b[(size_t)ch * (CCLS * DDIM / 4) + col];

    #pragma unroll
    for (int off = 4; off < 64; off <<= 1) {
        s.x += __shfl_xor(s.x, off);
        s.y += __shfl_xor(s.y, off);
        s.z += __shfl_xor(s.z, off);
        s.w += __shfl_xor(s.w, off);
    }

    __shared__ f32x4 lred[4][4];
    if (l < 4) lred[w][l] = s;
    __syncthreads();
    if (threadIdx.x < 4) {
        f32x4 t = (lred[0][threadIdx.x] + lred[1][threadIdx.x]) +
                  (lred[2][threadIdx.x] + lred[3][threadIdx.x]);
        reinterpret_cast<f32x4*>(out)[(size_t)v * (CCLS * DDIM / 4) + colbase + threadIdx.x] = t;
    }
}

// ---------------------------------------------------------------------------
extern "C" void kernel_launch(void* const* d_in, const int* in_sizes, int n_in,
                              void* d_out, int out_size, void* d_ws, size_t ws_size,
                              hipStream_t stream) {
    const int*   y = (const int*)d_in[0];         // [N, 10]
    const float* x = (const float*)d_in[1];       // [V, N, 256]
    float* out = (float*)d_out;                   // [V, 2560]

    const int N = in_sizes[0] / CCLS;             // 200000
    const int V = in_sizes[1] / (N * DDIM);       // 2

    // Ensure rows_per_chunk <= RPC_MAX (LDS mask table size).
    int nchunk = NCHUNK;
    while ((N + nchunk - 1) / nchunk > RPC_MAX) nchunk += 64;
    const int rpc = (N + nchunk - 1) / nchunk;

    const size_t part_bytes = (size_t)V * nchunk * CCLS * DDIM * sizeof(float);
    dim3 grid(nchunk, V);

    if (ws_size >= part_bytes) {
        float* part = (float*)d_ws;
        masked_sum_kernel<0><<<grid, 256, 0, stream>>>(x, y, part, N, rpc, nchunk);
        reduce_parts_kernel<<<dim3(CCLS * DDIM / 16, V), 256, 0, stream>>>(part, out, nchunk);
    } else {
        hipMemsetAsync(d_out, 0, (size_t)out_size * sizeof(float), stream);
        masked_sum_kernel<1><<<grid, 256, 0, stream>>>(x, y, out, N, rpc, nchunk);
    }
}